// Round 1
// baseline (17.593 us; speedup 1.0000x reference)
//
#include <hip/hip_runtime.h>

// out[i] = P(x[i]) / (|x[i]*Q(x[i])| + 1)
//   P = sum_{p=0}^{63} c[p]     x^p   (Horner, 63 fma)
//   Q = sum_{p=0}^{63} c[64+p]  x^p   (Horner, 63 fma), den = x*Q
// Coefficients are wave-uniform -> scalar loads via constant cache.
// 4 elements/thread (float4) -> 8 independent FMA chains for ILP.

__global__ __launch_bounds__(256) void rationals_kernel(
    const float* __restrict__ x,
    const float* __restrict__ coeff,
    float* __restrict__ out, int N) {
    int idx = (blockIdx.x * blockDim.x + threadIdx.x) * 4;
    if (idx >= N) return;

    float4 xv = *reinterpret_cast<const float4*>(x + idx);
    float xs[4] = {xv.x, xv.y, xv.z, xv.w};

    float num[4], den[4];
    float cn_top = coeff[63];
    float cd_top = coeff[127];
#pragma unroll
    for (int j = 0; j < 4; ++j) { num[j] = cn_top; den[j] = cd_top; }

#pragma unroll
    for (int p = 62; p >= 0; --p) {
        float cn = coeff[p];
        float cd = coeff[64 + p];
#pragma unroll
        for (int j = 0; j < 4; ++j) {
            num[j] = fmaf(num[j], xs[j], cn);
            den[j] = fmaf(den[j], xs[j], cd);
        }
    }

    float4 o;
    float* op = &o.x;
#pragma unroll
    for (int j = 0; j < 4; ++j) {
        float d = den[j] * xs[j];          // exponents 1..64
        op[j] = num[j] / (fabsf(d) + 1.0f);
    }
    *reinterpret_cast<float4*>(out + idx) = o;
}

extern "C" void kernel_launch(void* const* d_in, const int* in_sizes, int n_in,
                              void* d_out, int out_size, void* d_ws, size_t ws_size,
                              hipStream_t stream) {
    const float* x     = (const float*)d_in[0];
    const float* coeff = (const float*)d_in[1];
    // d_in[2]=n(63), d_in[3]=m(64) -- fixed by the problem, hard-coded above.
    float* out = (float*)d_out;
    int N = in_sizes[0];  // 4194304, divisible by 4

    int threads = 256;
    int elems_per_block = threads * 4;
    int blocks = (N + elems_per_block - 1) / elems_per_block;  // 4096
    rationals_kernel<<<blocks, threads, 0, stream>>>(x, coeff, out, N);
}

// Round 2
// 16.956 us; speedup vs baseline: 1.0376x; 1.0376x over previous
//
#include <hip/hip_runtime.h>

// out[i] = P(x[i]) / (|x[i]*Q(x[i])| + 1)
// Packed Horner: h[j] = {num_j, den_j} (v2f), one v_pk_fma_f32 per
// coefficient-pair per element. Coefficient pair {c[p], c[64+p]} is
// wave-uniform; {x,x} splat hoisted out of the loop.
// Fast reciprocal (v_rcp_f32) instead of precise div: denom >= 1, |num| <~ 50,
// rel err ~1e-6 -> abs err ~5e-5, threshold 0.4275.

typedef float v2f __attribute__((ext_vector_type(2)));

#define EPT 8  // elements per thread

__global__ __launch_bounds__(256) void rationals_kernel(
    const float* __restrict__ x,
    const float* __restrict__ coeff,
    float* __restrict__ out, int N) {
    int idx = (blockIdx.x * blockDim.x + threadIdx.x) * EPT;
    if (idx >= N) return;

    float xs[EPT];
    float4 xa = *reinterpret_cast<const float4*>(x + idx);
    float4 xb = *reinterpret_cast<const float4*>(x + idx + 4);
    xs[0] = xa.x; xs[1] = xa.y; xs[2] = xa.z; xs[3] = xa.w;
    xs[4] = xb.x; xs[5] = xb.y; xs[6] = xb.z; xs[7] = xb.w;

    v2f xx[EPT], h[EPT];
    float cn_top = coeff[63];
    float cd_top = coeff[127];
#pragma unroll
    for (int j = 0; j < EPT; ++j) {
        xx[j] = (v2f){xs[j], xs[j]};
        h[j]  = (v2f){cn_top, cd_top};
    }

#pragma unroll
    for (int p = 62; p >= 0; --p) {
        v2f c2 = {coeff[p], coeff[64 + p]};  // wave-uniform pair
#pragma unroll
        for (int j = 0; j < EPT; ++j)
            h[j] = __builtin_elementwise_fma(h[j], xx[j], c2);
    }

    float o[EPT];
#pragma unroll
    for (int j = 0; j < EPT; ++j) {
        float den = h[j].y * xs[j];          // exponents 1..64
        o[j] = h[j].x * __builtin_amdgcn_rcpf(fabsf(den) + 1.0f);
    }
    *reinterpret_cast<float4*>(out + idx)     = (float4){o[0], o[1], o[2], o[3]};
    *reinterpret_cast<float4*>(out + idx + 4) = (float4){o[4], o[5], o[6], o[7]};
}

extern "C" void kernel_launch(void* const* d_in, const int* in_sizes, int n_in,
                              void* d_out, int out_size, void* d_ws, size_t ws_size,
                              hipStream_t stream) {
    const float* x     = (const float*)d_in[0];
    const float* coeff = (const float*)d_in[1];
    float* out = (float*)d_out;
    int N = in_sizes[0];  // 4194304, divisible by EPT

    int threads = 256;
    int elems_per_block = threads * EPT;
    int blocks = (N + elems_per_block - 1) / elems_per_block;  // 2048
    rationals_kernel<<<blocks, threads, 0, stream>>>(x, coeff, out, N);
}